// Round 1
// 452.656 us; speedup vs baseline: 1.0667x; 1.0667x over previous
//
#include <hip/hip_runtime.h>

typedef unsigned short u16;
typedef __bf16 bf16x8 __attribute__((ext_vector_type(8)));
typedef float f32x4v __attribute__((ext_vector_type(4)));
typedef u16 u16x8 __attribute__((ext_vector_type(8)));

__device__ __forceinline__ u16 f2bf(float f) {
  union { float f; unsigned u; } v; v.f = f;
  unsigned r = v.u + 0x7fffu + ((v.u >> 16) & 1u);  // round-to-nearest-even
  return (u16)(r >> 16);
}
__device__ __forceinline__ float bf2f(u16 h) {
  union { unsigned u; float f; } v; v.u = ((unsigned)h) << 16;
  return v.f;
}

#define G2L16(g, l)                                                            \
  __builtin_amdgcn_global_load_lds((__attribute__((address_space(1))) void*)(g), \
                                   (__attribute__((address_space(3))) void*)(l), 16, 0, 0)

// ---------- transpose + fp32->bf16, 64x64 tiles, float4 loads ---------------
__global__ __launch_bounds__(256) void k_transpose2(const float* __restrict__ W1,
                                                    u16* __restrict__ W1T,
                                                    const float* __restrict__ W2,
                                                    u16* __restrict__ W2gT,
                                                    const float* __restrict__ g1,
                                                    const float* __restrict__ bt1,
                                                    float* __restrict__ w2ps,
                                                    float* __restrict__ w2pc) {
  __shared__ float tile[64][65];
  int bid = blockIdx.x;
  const float* in;
  u16* out;
  int R, C, bx, by, fold;
  if (bid < 2048) {            // W1: 32 row-tiles x 64 col-tiles
    in = W1; out = W1T; R = 2048; C = 4096; fold = 0;
    bx = bid & 63; by = bid >> 6;
  } else {                     // W2: 64 row-tiles x 32 col-tiles
    bid -= 2048;
    in = W2; out = W2gT; R = 4096; C = 2048; fold = 1;
    bx = bid & 31; by = bid >> 5;
  }
  const int c0 = bx * 64, r0 = by * 64;
  const int t = threadIdx.x;
  const int tc = (t & 15) * 4, tr = t >> 4;
#pragma unroll
  for (int i = 0; i < 4; ++i) {
    int r = tr + i * 16;
    f32x4v v = *(const f32x4v*)(in + (size_t)(r0 + r) * C + c0 + tc);
    tile[r][tc] = v[0]; tile[r][tc + 1] = v[1];
    tile[r][tc + 2] = v[2]; tile[r][tc + 3] = v[3];
  }
  __syncthreads();
  const int oc = t >> 2;        // output row (= input col) 0..63
  const int rb = (t & 3) * 16;  // 16 input rows each
  float gv[16];
#pragma unroll
  for (int i = 0; i < 16; ++i) gv[i] = fold ? g1[r0 + rb + i] : 1.f;
  u16x8 o0, o1;
#pragma unroll
  for (int i = 0; i < 8; ++i) o0[i] = f2bf(tile[rb + i][oc] * gv[i]);
#pragma unroll
  for (int i = 0; i < 8; ++i) o1[i] = f2bf(tile[rb + 8 + i][oc] * gv[8 + i]);
  *(u16x8*)(out + (size_t)(c0 + oc) * R + r0 + rb) = o0;
  *(u16x8*)(out + (size_t)(c0 + oc) * R + r0 + rb + 8) = o1;
  if (fold) {
    float ps = 0.f, pc = 0.f;
#pragma unroll
    for (int i = 0; i < 16; ++i) {
      float w = tile[rb + i][oc];
      ps += gv[i] * w;
      pc += bt1[r0 + rb + i] * w;
    }
    ps += __shfl_down(ps, 2, 4); ps += __shfl_down(ps, 1, 4);
    pc += __shfl_down(pc, 2, 4); pc += __shfl_down(pc, 1, 4);
    if ((t & 3) == 0) {
      w2ps[(size_t)by * 2048 + c0 + oc] = ps;
      w2pc[(size_t)by * 2048 + c0 + oc] = pc;
    }
  }
}

// -------- PQ table, split over (khalf, chalf): 512 blocks, no atomics -------
__global__ __launch_bounds__(256) void k_pq(const float* __restrict__ x1,
                                            const float* __restrict__ We,
                                            float* __restrict__ pq0,
                                            float* __restrict__ pq1) {
  const int n0 = blockIdx.x * 64;
  const int ep = blockIdx.y;  // e*2+p
  const int e = ep >> 1, p = ep & 1;
  const int khalf = blockIdx.z & 1;
  const int chalf = blockIdx.z >> 1;
  const int ks = khalf * 512;
  float* pq = khalf ? pq1 : pq0;
  __shared__ float As[32][33];
  __shared__ float Bs[32][68];
  const int t = threadIdx.x;
  const int tx = t & 15, ty = t >> 4;
  float acc[2][4] = {};
  const float* wbase = We + (size_t)e * 2048 * 1024 + (size_t)p * 1024 * 1024;
  for (int k0 = ks; k0 < ks + 512; k0 += 32) {
#pragma unroll
    for (int i = 0; i < 4; ++i) {
      int ix = t + i * 256;
      As[ix >> 5][ix & 31] =
          x1[(size_t)(chalf * 32 + (ix >> 5)) * 1024 + k0 + (ix & 31)];
    }
#pragma unroll
    for (int i = 0; i < 8; ++i) {
      int ix = t + i * 256;
      Bs[ix >> 6][ix & 63] = wbase[(size_t)(k0 + (ix >> 6)) * 1024 + n0 + (ix & 63)];
    }
    __syncthreads();
#pragma unroll
    for (int kk = 0; kk < 32; ++kk) {
      float av[2];
#pragma unroll
      for (int i = 0; i < 2; ++i) av[i] = As[ty * 2 + i][kk];
      f32x4v bv = *(const f32x4v*)&Bs[kk][tx * 4];
#pragma unroll
      for (int i = 0; i < 2; ++i)
#pragma unroll
        for (int j = 0; j < 4; ++j) acc[i][j] += av[i] * bv[j];
    }
    __syncthreads();
  }
#pragma unroll
  for (int i = 0; i < 2; ++i) {
    float* dst = pq + ((size_t)ep * 64 + chalf * 32 + ty * 2 + i) * 1024 + n0 + tx * 4;
#pragma unroll
    for (int j = 0; j < 4; ++j) dst[j] = acc[i][j];
  }
}

// ---------------- build Y (8192 x 2048, bf16): [relu(P+Q+be) | x2] ----------
__global__ __launch_bounds__(256) void k_build_y(const float* __restrict__ pq0,
                                                 const float* __restrict__ pq1,
                                                 const float* __restrict__ x2,
                                                 const float* __restrict__ be,
                                                 const int* __restrict__ cp,
                                                 const int* __restrict__ vis,
                                                 u16* __restrict__ Y) {
  const int t = threadIdx.x;
  for (int rr = 0; rr < 8; ++rr) {
    const int b = blockIdx.x * 8 + rr;
    const int e = vis[b];
    u16x8 o;
    if (t < 128) {
      const int c0 = cp[2 * b], c1 = cp[2 * b + 1];
      const size_t po = ((size_t)(e * 2) * 64 + c0) * 1024 + t * 8;
      const size_t qo = ((size_t)(e * 2 + 1) * 64 + c1) * 1024 + t * 8;
      const float* B = be + e * 1024 + t * 8;
#pragma unroll
      for (int i = 0; i < 8; ++i) {
        float v = pq0[po + i] + pq1[po + i] + pq0[qo + i] + pq1[qo + i] + B[i];
        o[i] = f2bf(v > 0.f ? v : 0.f);
      }
      *(u16x8*)(Y + (size_t)b * 2048 + t * 8) = o;
    } else {
      const float* X = x2 + (size_t)b * 1024 + (size_t)(t - 128) * 8;
#pragma unroll
      for (int i = 0; i < 8; ++i) o[i] = f2bf(X[i]);
      *(u16x8*)(Y + (size_t)b * 2048 + 1024 + (size_t)(t - 128) * 8) = o;
    }
  }
}

// ============================================================================
// bf16 MFMA GEMM — 256x256 tile, BK=64, 8 waves (2Mx4N), 8-phase schedule
// with counted vmcnt (T3+T4), setprio around MFMA clusters (T5), XOR-chunk
// LDS swizzle (conflict-free, both-sides: pre-swizzled global src + swizzled
// ds_read). 128 KiB LDS double-buffer -> 1 block/CU, 2 waves/SIMD.
//
// Per iteration: 2 K-tiles (T0@slot0 phases 1-4, T1@slot1 phases 5-8).
// Quadrant order (mh,nh) = (0,0),(0,1),(1,0),(1,1):
//   B-half of a slot is last ds_read in phase 2 (resp. 6), A-half in 3 (7).
// Staging (1 half-tile = 2 global_load_lds per wave, per phase):
//   ph1: A0_T1@s1  ph2: A1_T1@s1  ph3: B0_T2@s0  ph4: B1_T2@s0
//   ph5: A0_T2@s0  ph6: A1_T2@s0  ph7: B0_T3@s1  ph8: B1_T3@s1
// vmcnt(4) ONLY at ph4 (T1 must be landed; newest 4 loads = ph3+ph4) and
// ph8 (T2 landed; newest 4 = ph7+ph8). Never drains to 0 in the loop.
// ============================================================================
#define BARRIER __builtin_amdgcn_s_barrier()
#define WLG0                                                    \
  do {                                                          \
    asm volatile("s_waitcnt lgkmcnt(0)" ::: "memory");          \
    __builtin_amdgcn_sched_barrier(0);                          \
  } while (0)
#define WVM(n) asm volatile("s_waitcnt vmcnt(" #n ")" ::: "memory")

template <int MODE>
__global__ __launch_bounds__(512, 2) void k_gemm(const u16* __restrict__ A,
                                                 const u16* __restrict__ BT,
                                                 const float* __restrict__ bias,
                                                 const float2* __restrict__ stats,
                                                 const float* __restrict__ s1,
                                                 const float* __restrict__ c1b,
                                                 const float* __restrict__ gw3,
                                                 float2* __restrict__ sp_out,
                                                 float4* __restrict__ part,
                                                 u16* __restrict__ C,
                                                 int M, int N, int K) {
  // [buf(2)][ab(2)][half(2)][128 rows][64 k] bf16 = 128 KiB
  __shared__ u16 smem[65536];
  const int tid = threadIdx.x;
  const int lane = tid & 63;
  const int wave = tid >> 6;
  const int wm = wave >> 2;   // 0..1 -> 128 output rows
  const int wn = wave & 3;    // 0..3 -> 64 output cols

  // Bijective XCD swizzle: each XCD walks a (ny/8)-row stripe column-major.
  const int nx = gridDim.x, ny = gridDim.y;
  const int bid = blockIdx.y * nx + blockIdx.x;
  const int stripe = ny >> 3;                  // ny % 8 == 0 here
  const int xcd = bid & 7;
  const int loc = bid >> 3;
  const int by = xcd * stripe + (loc % stripe);
  const int bx = loc / stripe;
  const int tileM = by * 256;
  const int tileN = bx * 256;

  f32x4v acc[8][4];
#pragma unroll
  for (int i = 0; i < 8; ++i)
#pragma unroll
    for (int j = 0; j < 4; ++j) acc[i][j] = (f32x4v){0.f, 0.f, 0.f, 0.f};

  // ---- staging addresses: row = tid>>3 (0..63, +64 for 2nd issue),
  //      phys chunk tid&7 holds logical chunk (tid&7)^(row&7) (pre-swizzled
  //      global source; LDS dest stays linear for global_load_lds).
  const int srow = tid >> 3;
  const int slc = ((tid & 7) ^ (srow & 7)) * 8;
  const u16* aG = A + (size_t)(tileM + srow) * K + slc;
  const u16* bG = BT + (size_t)(tileN + srow) * K + slc;

#define STAGE(ab, h, buf, kt)                                                  \
  do {                                                                         \
    u16* dst_ = smem + (buf) * 32768 + (ab) * 16384 + (h) * 8192 + tid * 8;    \
    const u16* g_ = ((ab) ? bG : aG) + (size_t)(h) * 128 * K + (size_t)(kt) * 64; \
    G2L16(g_, dst_);                                                           \
    G2L16(g_ + (size_t)64 * K, dst_ + 4096);                                   \
  } while (0)

  // ---- fragment read addressing (swizzled): row&7 == lane&7 for both A,B.
  const int kp0 = (((lane >> 4) ^ (lane & 7)) * 8);
  const int kp1 = kp0 ^ 32;
  const int awoff = wm * 8192 + (lane & 15) * 64;
  const int bwoff = (wn >> 1) * 8192 + ((wn & 1) * 64 + (lane & 15)) * 64;

  bf16x8 af[2][4], bf[2][4];

#define RD_A(buf, mh)                                                          \
  do {                                                                         \
    const u16* ap_ = smem + (buf) * 32768 + awoff;                             \
    _Pragma("unroll") for (int q = 0; q < 4; ++q) {                            \
      af[0][q] = *(const bf16x8*)(ap_ + ((mh) * 4 + q) * 1024 + kp0);          \
      af[1][q] = *(const bf16x8*)(ap_ + ((mh) * 4 + q) * 1024 + kp1);          \
    }                                                                          \
  } while (0)

#define RD_B(buf, nh)                                                          \
  do {                                                                         \
    const u16* bp_ = smem + (buf) * 32768 + 16384 + bwoff;                     \
    _Pragma("unroll") for (int q = 0; q < 2; ++q) {                            \
      bf[0][(nh) * 2 + q] = *(const bf16x8*)(bp_ + ((nh) * 2 + q) * 1024 + kp0); \
      bf[1][(nh) * 2 + q] = *(const bf16x8*)(bp_ + ((nh) * 2 + q) * 1024 + kp1); \
    }                                                                          \
  } while (0)

#define QUAD(mh, nh)                                                           \
  do {                                                                         \
    __builtin_amdgcn_s_setprio(1);                                             \
    _Pragma("unroll") for (int kh = 0; kh < 2; ++kh)                           \
    _Pragma("unroll") for (int q = 0; q < 4; ++q)                              \
    _Pragma("unroll") for (int p = 0; p < 2; ++p)                              \
      acc[(mh) * 4 + q][(nh) * 2 + p] = __builtin_amdgcn_mfma_f32_16x16x32_bf16( \
          af[kh][q], bf[kh][(nh) * 2 + p], acc[(mh) * 4 + q][(nh) * 2 + p], 0, 0, 0); \
    __builtin_amdgcn_s_setprio(0);                                             \
  } while (0)

  const int nkt = K >> 6;       // 64-wide K-tiles (32 or 64)
  const int niter = nkt >> 1;   // 2 K-tiles per iteration

  // ---- prologue: T0 fully + B-halves of T1 (matches steady-state order)
  STAGE(1, 0, 0, 0);  // B0 T0
  STAGE(1, 1, 0, 0);  // B1 T0
  STAGE(0, 0, 0, 0);  // A0 T0
  STAGE(0, 1, 0, 0);  // A1 T0
  STAGE(1, 0, 1, 1);  // B0 T1
  STAGE(1, 1, 1, 1);  // B1 T1
  WVM(4);             // T0's 8 loads landed; T1's B (4) may be in flight
  BARRIER;

  for (int it = 0; it < niter; ++it) {
    const int t1 = 2 * it + 1;
    int t2 = 2 * it + 2; if (t2 >= nkt) t2 = nkt - 1;   // clamped tail
    int t3 = 2 * it + 3; if (t3 >= nkt) t3 = nkt - 1;   // prefetch (unused)
    // phase 1: quad(0,0) on T0; stage A0_T1
    RD_A(0, 0); RD_B(0, 0);
    STAGE(0, 0, 1, t1);
    BARRIER; WLG0; QUAD(0, 0); BARRIER;
    // phase 2: quad(0,1); stage A1_T1   (B@slot0 free after this phase)
    RD_B(0, 1);
    STAGE(0, 1, 1, t1);
    BARRIER; WLG0; QUAD(0, 1); BARRIER;
    // phase 3: quad(1,0); stage B0_T2 -> slot0 (B free since end ph2)
    RD_A(0, 1);
    STAGE(1, 0, 0, t2);
    BARRIER; WLG0; QUAD(1, 0); BARRIER;
    // phase 4: quad(1,1); stage B1_T2; counted wait: T1 landed
    STAGE(1, 1, 0, t2);
    BARRIER; QUAD(1, 1); WVM(4); BARRIER;
    // phase 5: quad(0,0) on T1; stage A0_T2 -> slot0 (A free since end ph3)
    RD_A(1, 0); RD_B(1, 0);
    STAGE(0, 0, 0, t2);
    BARRIER; WLG0; QUAD(0, 0); BARRIER;
    // phase 6: quad(0,1); stage A1_T2
    RD_B(1, 1);
    STAGE(0, 1, 0, t2);
    BARRIER; WLG0; QUAD(0, 1); BARRIER;
    // phase 7: quad(1,0); stage B0_T3 -> slot1 (B@slot1 free after ph6)
    RD_A(1, 1);
    STAGE(1, 0, 1, t3);
    BARRIER; WLG0; QUAD(1, 0); BARRIER;
    // phase 8: quad(1,1); stage B1_T3; counted wait: T2 landed
    STAGE(1, 1, 1, t3);
    BARRIER; QUAD(1, 1); WVM(4); BARRIER;
  }

  // ---- epilogue: C/D layout col = lane&15, row = (lane>>4)*4 + reg
  const int crow = tileM + wm * 128 + (lane >> 4) * 4;
  const int ccol = tileN + wn * 64 + (lane & 15);
  float cv0[4], cv1[4], cg[4];
#pragma unroll
  for (int ni = 0; ni < 4; ++ni) {
    const int c = ccol + ni * 16;
    if (MODE == 0) {
      cv0[ni] = bias[c];
    } else {
      cv0[ni] = s1[c];
      cv1[ni] = c1b[c];
      cg[ni] = gw3[c];
    }
  }
  const int cb = bx * 4 + wn;  // 64-col block index: [0,64) G1, [0,32) G2
#pragma unroll
  for (int mi = 0; mi < 8; ++mi) {
#pragma unroll
    for (int r = 0; r < 4; ++r) {
      const int row = crow + mi * 16 + r;
      if (MODE == 0) {
        float s_ = 0.f, ss_ = 0.f;
#pragma unroll
        for (int ni = 0; ni < 4; ++ni) {
          float v = acc[mi][ni][r] + cv0[ni];
          v = v > 0.f ? v : 0.f;
          s_ += v; ss_ += v * v;
          C[(size_t)row * N + ccol + ni * 16] = f2bf(v);
        }
#pragma unroll
        for (int off = 8; off >= 1; off >>= 1) {
          s_ += __shfl_xor(s_, off, 16);
          ss_ += __shfl_xor(ss_, off, 16);
        }
        if ((lane & 15) == 0)
          sp_out[(size_t)row * 64 + cb] = make_float2(s_, ss_);
      } else {
        float2 st = stats[row];
        const float m = st.x, rs = st.y;
        float s_ = 0.f, ss_ = 0.f, d_ = 0.f;
#pragma unroll
        for (int ni = 0; ni < 4; ++ni) {
          float v = rs * acc[mi][ni][r] - rs * m * cv0[ni] + cv1[ni];
          v = v > 0.f ? v : 0.f;
          s_ += v; ss_ += v * v; d_ += v * cg[ni];
        }
#pragma unroll
        for (int off = 8; off >= 1; off >>= 1) {
          s_ += __shfl_xor(s_, off, 16);
          ss_ += __shfl_xor(ss_, off, 16);
          d_ += __shfl_xor(d_, off, 16);
        }
        if ((lane & 15) == 0)
          part[(size_t)row * 32 + cb] = make_float4(s_, ss_, d_, 0.f);
      }
    }
  }
}

// ---- reduce: LN1 stats (coalesced sp), s1/c1b, gw3=g2*W3, SG/CB scalars ----
__global__ __launch_bounds__(256) void k_reduce(const float2* __restrict__ sp,
                                                float2* __restrict__ stats,
                                                const float* __restrict__ w2ps,
                                                const float* __restrict__ w2pc,
                                                const float* __restrict__ b2,
                                                float* __restrict__ s1,
                                                float* __restrict__ c1b,
                                                const float* __restrict__ g2,
                                                const float* __restrict__ bt2,
                                                const float* __restrict__ W3,
                                                float* __restrict__ gw3,
                                                float* __restrict__ scal) {
  __shared__ float red[8];
  const int bid = blockIdx.x;
  const int t = threadIdx.x;
  if (bid < 32) {
    const int g = t >> 4, l = t & 15;
#pragma unroll 1
    for (int rr = 0; rr < 16; ++rr) {
      const int row = bid * 256 + rr * 16 + g;
      float s = 0.f, ss = 0.f;
#pragma unroll
      for (int i = 0; i < 4; ++i) {
        float2 p = sp[(size_t)row * 64 + l * 4 + i];
        s += p.x; ss += p.y;
      }
#pragma unroll
      for (int off = 8; off >= 1; off >>= 1) {
        s += __shfl_xor(s, off, 16);
        ss += __shfl_xor(ss, off, 16);
      }
      if (l == 0) {
        float m = s * (1.f / 4096.f);
        float var = ss * (1.f / 4096.f) - m * m;
        stats[row] = make_float2(m, rsqrtf(var + 1e-5f));
      }
    }
  } else if (bid < 40) {
    const int nn = (bid - 32) * 256 + t;
    float s = 0.f, c = 0.f;
    for (int kb = 0; kb < 64; ++kb) {
      s += w2ps[(size_t)kb * 2048 + nn];
      c += w2pc[(size_t)kb * 2048 + nn];
    }
    s1[nn] = s;
    c1b[nn] = c + b2[nn];
  } else {
    float sg = 0.f, cb = 0.f;
    for (int i = 0; i < 8; ++i) {
      int c = i * 256 + t;
      float w3 = W3[c];
      float gv = g2[c] * w3;
      gw3[c] = gv;
      sg += gv;
      cb += bt2[c] * w3;
    }
#pragma unroll
    for (int off = 32; off > 0; off >>= 1) {
      sg += __shfl_down(sg, off, 64);
      cb += __shfl_down(cb, off, 64);
    }
    const int lane = t & 63, wv = t >> 6;
    if (lane == 0) { red[wv] = sg; red[4 + wv] = cb; }
    __syncthreads();
    if (t == 0) {
      scal[0] = red[0] + red[1] + red[2] + red[3];
      scal[1] = red[4] + red[5] + red[6] + red[7];
    }
  }
}

// ------- final: out[row] = sigmoid(rs*D - rs*m*SG + CB + b3) ----------------
__global__ __launch_bounds__(256) void k_final(const float4* __restrict__ part,
                                               const float* __restrict__ scal,
                                               const float* __restrict__ b3,
                                               float* __restrict__ out) {
  const int t = threadIdx.x;
  const int g = t >> 4, l = t & 15;
  const int row = blockIdx.x * 16 + g;
  float4 a = part[(size_t)row * 32 + l * 2];
  float4 b = part[(size_t)row * 32 + l * 2 + 1];
  float S = a.x + b.x, SS = a.y + b.y, D = a.z + b.z;
#pragma unroll
  for (int off = 8; off >= 1; off >>= 1) {
    S += __shfl_xor(S, off, 16);
    SS += __shfl_xor(SS, off, 16);
    D += __shfl_xor(D, off, 16);
  }
  if (l == 0) {
    float m = S * (1.f / 2048.f);
    float rs = rsqrtf(SS * (1.f / 2048.f) - m * m + 1e-5f);
    float logit = rs * D - rs * m * scal[0] + scal[1] + b3[0];
    out[row] = 1.f / (1.f + expf(-logit));
  }
}

extern "C" void kernel_launch(void* const* d_in, const int* in_sizes, int n_in,
                              void* d_out, int out_size, void* d_ws, size_t ws_size,
                              hipStream_t stream) {
  const float* x1 = (const float*)d_in[0];
  const float* x2 = (const float*)d_in[1];
  const float* We = (const float*)d_in[2];
  const float* be = (const float*)d_in[3];
  const float* W1 = (const float*)d_in[4];
  const float* b1 = (const float*)d_in[5];
  const float* g1 = (const float*)d_in[6];
  const float* bt1 = (const float*)d_in[7];
  const float* W2 = (const float*)d_in[8];
  const float* b2 = (const float*)d_in[9];
  const float* g2 = (const float*)d_in[10];
  const float* bt2 = (const float*)d_in[11];
  const float* W3 = (const float*)d_in[12];
  const float* b3 = (const float*)d_in[13];
  const int* cp = (const int*)d_in[14];
  const int* vis = (const int*)d_in[15];
  float* out = (float*)d_out;

  char* ws = (char*)d_ws;
  u16* W1T  = (u16*)(ws);                  // 4096x2048 bf16 = 16 MiB
  u16* W2gT = (u16*)(ws + 16777216);       // 2048x4096 bf16 = 16 MiB
  u16* Y    = (u16*)(ws + 33554432);       // 8192x2048 bf16 = 32 MiB
  u16* H1   = (u16*)(ws + 67108864);       // 8192x4096 bf16 = 64 MiB
  float* PQ0 = (float*)(ws + 134217728);   // 2 MiB
  float* PQ1 = (float*)(ws + 136314880);   // 2 MiB
  float2* sp = (float2*)(ws + 134217728);
  float4* part = (float4*)(ws + 134217728);
  float2* stats = (float2*)(ws + 138412032);  // 64 KiB
  float* s1   = (float*)(ws + 138477568);     // 8 KiB
  float* c1b  = (float*)(ws + 138485760);     // 8 KiB
  float* w2ps = (float*)(ws + 138493952);     // 64x2048 f32 = 512 KiB
  float* w2pc = (float*)(ws + 139018240);     // 512 KiB
  float* gw3  = (float*)(ws + 139542528);     // 8 KiB
  float* scal = (float*)(ws + 139550720);     // 2 f32

  k_transpose2<<<4096, 256, 0, stream>>>(W1, W1T, W2, W2gT, g1, bt1, w2ps, w2pc);
  k_pq<<<dim3(16, 8, 4), 256, 0, stream>>>(x1, We, PQ0, PQ1);
  k_build_y<<<1024, 256, 0, stream>>>(PQ0, PQ1, x2, be, cp, vis, Y);
  k_gemm<0><<<dim3(16, 32), 512, 0, stream>>>(
      Y, W1T, b1, nullptr, nullptr, nullptr, nullptr, sp, nullptr, H1,
      8192, 4096, 2048);
  k_reduce<<<41, 256, 0, stream>>>(sp, stats, w2ps, w2pc, b2, s1, c1b,
                                   g2, bt2, W3, gw3, scal);
  k_gemm<1><<<dim3(8, 32), 512, 0, stream>>>(
      H1, W2gT, nullptr, stats, s1, c1b, gw3, nullptr, part, nullptr,
      8192, 2048, 4096);
  k_final<<<512, 256, 0, stream>>>(part, scal, b3, out);
}